// Round 5
// baseline (390.747 us; speedup 1.0000x reference)
//
#include <hip/hip_runtime.h>

// Problem constants (fixed by reference setup_inputs)
#define BB   2048   // batch
#define LL   20     // seq length
#define JJ   25     // joints
#define CC   256    // channels
#define FF   64     // filters
#define KK   4      // hops
#define JPAD 28     // padded row length for aligned float4 reads of M rows
#define MSZ  (JJ * JPAD)   // 700

typedef float f2 __attribute__((ext_vector_type(2)));
typedef float f4 __attribute__((ext_vector_type(4)));

// out[l,b,i,c] = sum_j M[l,i,j] * x[b,l,j,c]
// M[l,i,j]     = sum_k w[k,l] * A[i,j]^k   (elementwise power, Horner)
// w[k,l]       = sum_n kernel[n,k,l]
//
// Grid: LL * (BB/2) blocks; block = 256 threads = 2 batch-subs x 128 f2 cols.
// Loads issue FIRST (kern, A, then the 25-deep x burst) so HBM latency hides
// under the w-reduce/Horner/barrier preamble; launch_bounds(256,6) targets
// 6 waves/SIMD (VGPR cap 84) for better stream overlap.
__global__ __launch_bounds__(256, 6) void GCNLayer_72602127172024_kernel(
    const float* __restrict__ x,     // [B,L,J,C]
    const float* __restrict__ A,     // [J,J]
    const float* __restrict__ kern,  // [F,K,L]
    float* __restrict__ out)         // [L,B,J,C]
{
    __shared__ float w_sh[KK];
    __shared__ __align__(16) float Ms[MSZ];  // Ms[i*JPAD+j], pad zeroed

    const int tid = threadIdx.x;
    const int gid = blockIdx.x;
    const int l   = gid >> 10;          // / (BB/2) == /1024
    const int bb  = (gid & 1023) << 1;  // base batch of this block

    // ---------- issue ALL global loads up front, oldest = preamble deps ----
    // 1) kern element for the w-reduce (wave k, lane n)
    const int k    = tid >> 6;
    const int lane = tid & 63;
    const float kv = kern[lane * (KK * LL) + k * LL + l];

    // 2) A elements for this thread's (up to 3) M entries, index-clamped
    //    so the loads can issue unconditionally before the x burst.
    const int e0 = tid, e1 = tid + 256, e2 = tid + 512;
    const int i0 = e0 / JPAD, j0 = e0 - i0 * JPAD;
    const int i1 = e1 / JPAD, j1 = e1 - i1 * JPAD;
    const int i2 = (e2 < MSZ) ? e2 / JPAD : 0;
    const int j2 = (e2 < MSZ) ? e2 - i2 * JPAD : 0;
    const float a0 = A[(j0 < JJ) ? i0 * JJ + j0 : 0];
    const float a1 = A[(j1 < JJ) ? i1 * JJ + j1 : 0];
    const float a2 = A[(j2 < JJ) ? i2 * JJ + j2 : 0];

    // 3) the 25-deep x burst (newest; preamble waits use vmcnt(N), not 0)
    const int bsub = tid >> 7;        // 0..1
    const int c2   = tid & 127;       // float2 column (CC/2 == 128)
    const int b    = bb + bsub;

    const f2* __restrict__ xin =
        reinterpret_cast<const f2*>(x) + ((b * LL + l) * JJ) * 128 + c2;
    f2* __restrict__ oout =
        reinterpret_cast<f2*>(out) + ((l * BB + b) * JJ) * 128 + c2;

    f2 xv[JJ];
#pragma unroll
    for (int j = 0; j < JJ; ++j)
        xv[j] = __builtin_nontemporal_load(xin + j * 128);

    // ---------- preamble (overlaps x-load latency) ----------
    {
        float v = kv;                 // waits only for the kern load
        v += __shfl_xor(v, 32, 64);
        v += __shfl_xor(v, 16, 64);
        v += __shfl_xor(v, 8, 64);
        v += __shfl_xor(v, 4, 64);
        v += __shfl_xor(v, 2, 64);
        v += __shfl_xor(v, 1, 64);
        if (lane == 0) w_sh[k] = v;
    }
    __syncthreads();

    const float w0 = w_sh[0], w1 = w_sh[1], w2 = w_sh[2], w3 = w_sh[3];

    // Horner; a=0 -> w0 (elementwise 0^0 == 1). Pad entries (j>=JJ) -> 0.
    Ms[e0] = (j0 < JJ) ? w0 + a0 * (w1 + a0 * (w2 + a0 * w3)) : 0.0f;
    Ms[e1] = (j1 < JJ) ? w0 + a1 * (w1 + a1 * (w2 + a1 * w3)) : 0.0f;
    if (e2 < MSZ)
        Ms[e2] = (j2 < JJ) ? w0 + a2 * (w1 + a2 * (w2 + a2 * w3)) : 0.0f;
    __syncthreads();

    // ---------- compute: per joint i, M row = 7 f4 LDS broadcasts ----------
#pragma unroll
    for (int i = 0; i < JJ; ++i) {
        const f4* mrow = reinterpret_cast<const f4*>(Ms + i * JPAD);
        f2 acc = {0.0f, 0.0f};
#pragma unroll
        for (int j4 = 0; j4 < 7; ++j4) {
            const f4 m4 = mrow[j4];
#pragma unroll
            for (int comp = 0; comp < 4; ++comp) {
                const int j = j4 * 4 + comp;
                if (j < JJ) {   // compile-time pruned (full unroll)
                    const float m = m4[comp];
                    acc.x = fmaf(m, xv[j].x, acc.x);
                    acc.y = fmaf(m, xv[j].y, acc.y);
                }
            }
        }
        __builtin_nontemporal_store(acc, oout + i * 128);
    }
}

extern "C" void kernel_launch(void* const* d_in, const int* in_sizes, int n_in,
                              void* d_out, int out_size, void* d_ws, size_t ws_size,
                              hipStream_t stream) {
    const float* x    = (const float*)d_in[0];   // [B,L,J,C]
    const float* A    = (const float*)d_in[1];   // [J,J]
    const float* kern = (const float*)d_in[2];   // [F,K,L]
    float* out        = (float*)d_out;           // [L,B,J,C]

    const int grid = LL * (BB / 2);  // 20480 blocks
    GCNLayer_72602127172024_kernel<<<grid, 256, 0, stream>>>(x, A, kern, out);
}

// Round 6
// 388.607 us; speedup vs baseline: 1.0055x; 1.0055x over previous
//
#include <hip/hip_runtime.h>

// Problem constants (fixed by reference setup_inputs)
#define BB   2048   // batch
#define LL   20     // seq length
#define JJ   25     // joints
#define CC   256    // channels
#define FF   64     // filters
#define KK   4      // hops
#define JPAD 28     // padded row length (16B-aligned rows for s_load_dwordx4)
#define MSZ  (JJ * JPAD)   // 700 floats per l-slice of M

typedef float f2 __attribute__((ext_vector_type(2)));
typedef float f4 __attribute__((ext_vector_type(4)));

// ---------------------------------------------------------------------------
// Kernel 1 (tiny, ~3us): M[l,i,j] = sum_k w[k,l]*A[i,j]^k, w[k,l]=sum_n kern[n,k,l]
// One block per l; writes [LL][JJ][JPAD] floats (pad zeroed) into d_ws.
// ---------------------------------------------------------------------------
__global__ __launch_bounds__(256) void GCN_precompute_M(
    const float* __restrict__ A,     // [J,J]
    const float* __restrict__ kern,  // [F,K,L]
    float* __restrict__ Mg)          // [LL][JJ][JPAD]
{
    const int l = blockIdx.x;
    __shared__ float w_sh[KK];

    {
        const int k    = threadIdx.x >> 6;   // wave id == hop (KK==4 waves)
        const int lane = threadIdx.x & 63;   // filter index (FF==64 exactly)
        float v = kern[lane * (KK * LL) + k * LL + l];
        v += __shfl_xor(v, 32, 64);
        v += __shfl_xor(v, 16, 64);
        v += __shfl_xor(v, 8, 64);
        v += __shfl_xor(v, 4, 64);
        v += __shfl_xor(v, 2, 64);
        v += __shfl_xor(v, 1, 64);
        if (lane == 0) w_sh[k] = v;
    }
    __syncthreads();

    const float w0 = w_sh[0], w1 = w_sh[1], w2 = w_sh[2], w3 = w_sh[3];

    for (int e = threadIdx.x; e < MSZ; e += 256) {
        const int i = e / JPAD;
        const int j = e - i * JPAD;
        float m = 0.0f;
        if (j < JJ) {
            const float a = A[i * JJ + j];
            m = w0 + a * (w1 + a * (w2 + a * w3));   // Horner; a=0 -> w0 (0^0==1)
        }
        Mg[l * MSZ + e] = m;
    }
}

// ---------------------------------------------------------------------------
// Kernel 2 (hot): NO LDS, NO barriers. M rows come in through the SCALAR pipe
// (uniform loads from __restrict__ const pointer -> s_load through K$), so the
// inner loop is pure v_fmac_f32 vacc, s_m, v_xv. The LDS pipe (previously
// ~175 ds_read_b128/wave = up to 84% of the per-wave HBM cycle budget) is now
// completely idle; vector memory carries only the x/out streams.
// Grid: LL*(BB/2); block = 256 threads = 2 batch-subs x 128 f2 cols.
// ---------------------------------------------------------------------------
__global__ __launch_bounds__(256, 6) void GCNLayer_72602127172024_kernel(
    const float* __restrict__ x,     // [B,L,J,C]
    const float* __restrict__ Mg,    // [LL][JJ][JPAD]
    float* __restrict__ out)         // [L,B,J,C]
{
    const int tid = threadIdx.x;
    const int gid = blockIdx.x;
    const int l   = gid >> 10;          // / (BB/2) == /1024
    const int bb  = (gid & 1023) << 1;  // base batch of this block

    const int bsub = tid >> 7;        // 0..1
    const int c2   = tid & 127;       // float2 column (CC/2 == 128)
    const int b    = bb + bsub;

    const f2* __restrict__ xin =
        reinterpret_cast<const f2*>(x) + ((b * LL + l) * JJ) * 128 + c2;
    f2* __restrict__ oout =
        reinterpret_cast<f2*>(out) + ((l * BB + b) * JJ) * 128 + c2;

    // Full [J] column slab into registers (25 x f2 = 50 VGPR), coalesced
    // 512B/wave-instr. Nontemporal: pure stream, no reuse.
    f2 xv[JJ];
#pragma unroll
    for (int j = 0; j < JJ; ++j)
        xv[j] = __builtin_nontemporal_load(xin + j * 128);

    // Uniform M base for this block's l (SGPR address).
    const float* __restrict__ Msl = Mg + l * MSZ;

    // Per output joint i: 25 scalar (s_load) M values + 50 v_fmac, store.
    // unroll 2 gives SMEM/VALU pipelining at ~60 SGPRs of row data (no spill).
#pragma unroll 2
    for (int i = 0; i < JJ; ++i) {
        const float* __restrict__ mrow = Msl + i * JPAD;
        f2 acc = {0.0f, 0.0f};
#pragma unroll
        for (int j = 0; j < JJ; ++j) {
            const float m = mrow[j];          // uniform -> scalar load
            acc.x = fmaf(m, xv[j].x, acc.x);
            acc.y = fmaf(m, xv[j].y, acc.y);
        }
        __builtin_nontemporal_store(acc, oout + i * 128);
    }
}

extern "C" void kernel_launch(void* const* d_in, const int* in_sizes, int n_in,
                              void* d_out, int out_size, void* d_ws, size_t ws_size,
                              hipStream_t stream) {
    const float* x    = (const float*)d_in[0];   // [B,L,J,C]
    const float* A    = (const float*)d_in[1];   // [J,J]
    const float* kern = (const float*)d_in[2];   // [F,K,L]
    float* out        = (float*)d_out;           // [L,B,J,C]
    float* Mg         = (float*)d_ws;            // [LL][JJ][JPAD] = 56 KB

    GCN_precompute_M<<<LL, 256, 0, stream>>>(A, kern, Mg);

    const int grid = LL * (BB / 2);  // 20480 blocks
    GCNLayer_72602127172024_kernel<<<grid, 256, 0, stream>>>(x, Mg, out);
}